// Round 1
// baseline (802.438 us; speedup 1.0000x reference)
//
#include <hip/hip_runtime.h>
#include <math.h>

#define BATCH 4
#define SEQ 4096
#define DMODEL 1024
#define HD 64
#define EE 192          // 3*HD
#define KSP 409         // max(1, int(4096*0.1))
#define SCALE 0.125f
#define LISTCAP 1024

__device__ __forceinline__ unsigned int fkey(float f) {
    unsigned int u = __float_as_uint(f);
    return (u & 0x80000000u) ? ~u : (u | 0x80000000u);
}

// ---------------- K1: QKV projection  qkv[m][e] = X[m][:] . W[e][:] ----------------
// BM=64, BN=64, BK=16; 256 threads; k-major LDS tiles (stride 68 avoids conflicts, keeps b128 align)
__global__ __launch_bounds__(256) void qkv_kernel(const float* __restrict__ X,
                                                  const float* __restrict__ W,
                                                  float* __restrict__ QKV) {
    __shared__ __align__(16) float Xs[16][68];
    __shared__ __align__(16) float Ws[16][68];
    const int t = threadIdx.x;
    const int m0 = blockIdx.x * 64;
    const int n0 = blockIdx.y * 64;
    const int ma = (t & 15) * 4;
    const int na = (t >> 4) * 4;
    const int lr = t >> 2;            // 0..63 (row within tile)
    const int lc = (t & 3) * 4;       // 0,4,8,12 (k within step)
    float acc[4][4] = {};
    for (int k0 = 0; k0 < DMODEL; k0 += 16) {
        __syncthreads();
        float4 xv = *(const float4*)&X[(size_t)(m0 + lr) * DMODEL + k0 + lc];
        Xs[lc + 0][lr] = xv.x; Xs[lc + 1][lr] = xv.y; Xs[lc + 2][lr] = xv.z; Xs[lc + 3][lr] = xv.w;
        float4 wv = *(const float4*)&W[(size_t)(n0 + lr) * DMODEL + k0 + lc];
        Ws[lc + 0][lr] = wv.x; Ws[lc + 1][lr] = wv.y; Ws[lc + 2][lr] = wv.z; Ws[lc + 3][lr] = wv.w;
        __syncthreads();
        #pragma unroll
        for (int kk = 0; kk < 16; ++kk) {
            float4 a4 = *(const float4*)&Xs[kk][ma];
            float4 b4 = *(const float4*)&Ws[kk][na];
            float a[4] = {a4.x, a4.y, a4.z, a4.w};
            float b[4] = {b4.x, b4.y, b4.z, b4.w};
            #pragma unroll
            for (int i = 0; i < 4; ++i)
                #pragma unroll
                for (int j = 0; j < 4; ++j)
                    acc[i][j] = fmaf(a[i], b[j], acc[i][j]);
        }
    }
    #pragma unroll
    for (int i = 0; i < 4; ++i) {
        float4 o = {acc[i][0], acc[i][1], acc[i][2], acc[i][3]};
        *(float4*)&QKV[(size_t)(m0 + ma + i) * EE + n0 + na] = o;
    }
}

// ---------------- K2: scores for one batch: S[i][j] = SCALE * q_i . k_j ----------------
// BM=BN=128, K=64 (single slab), 256 threads, 8x8 acc/thread, k-major LDS [64][128] (64 KiB total)
__global__ __launch_bounds__(256) void scores_kernel(const float* __restrict__ QKV,
                                                     float* __restrict__ Sc, int b) {
    __shared__ __align__(16) float Qs[64][128];
    __shared__ __align__(16) float Ks[64][128];
    const int t = threadIdx.x;
    const int i0 = blockIdx.y * 128;
    const int j0 = blockIdx.x * 128;
    const float* base = QKV + (size_t)b * SEQ * EE;
    #pragma unroll
    for (int u = 0; u < 8; ++u) {
        int g4 = t + 256 * u;          // 0..2047
        int r  = g4 >> 4;              // 0..127
        int c  = (g4 & 15) * 4;        // 0..60
        float4 qv = *(const float4*)&base[(size_t)(i0 + r) * EE + c];
        Qs[c + 0][r] = qv.x; Qs[c + 1][r] = qv.y; Qs[c + 2][r] = qv.z; Qs[c + 3][r] = qv.w;
        float4 kv = *(const float4*)&base[(size_t)(j0 + r) * EE + 64 + c];
        Ks[c + 0][r] = kv.x; Ks[c + 1][r] = kv.y; Ks[c + 2][r] = kv.z; Ks[c + 3][r] = kv.w;
    }
    __syncthreads();
    float acc[8][8] = {};
    const int ma = (t & 15) * 8;
    const int na = (t >> 4) * 8;
    #pragma unroll 4
    for (int kk = 0; kk < 64; ++kk) {
        float4 a0 = *(const float4*)&Qs[kk][ma];
        float4 a1 = *(const float4*)&Qs[kk][ma + 4];
        float4 b0 = *(const float4*)&Ks[kk][na];
        float4 b1 = *(const float4*)&Ks[kk][na + 4];
        float a[8] = {a0.x, a0.y, a0.z, a0.w, a1.x, a1.y, a1.z, a1.w};
        float bb[8] = {b0.x, b0.y, b0.z, b0.w, b1.x, b1.y, b1.z, b1.w};
        #pragma unroll
        for (int i = 0; i < 8; ++i)
            #pragma unroll
            for (int j = 0; j < 8; ++j)
                acc[i][j] = fmaf(a[i], bb[j], acc[i][j]);
    }
    #pragma unroll
    for (int i = 0; i < 8; ++i) {
        float* orow = Sc + (size_t)(i0 + ma + i) * SEQ + j0 + na;
        float4 o0 = {acc[i][0] * SCALE, acc[i][1] * SCALE, acc[i][2] * SCALE, acc[i][3] * SCALE};
        float4 o1 = {acc[i][4] * SCALE, acc[i][5] * SCALE, acc[i][6] * SCALE, acc[i][7] * SCALE};
        *(float4*)&orow[0] = o0;
        *(float4*)&orow[4] = o1;
    }
}

// ---------------- K3: per-row exact top-K select + softmax + P.V ----------------
__global__ __launch_bounds__(256) void topk_attn_kernel(const float* __restrict__ QKV,
                                                        const float* __restrict__ Sc,
                                                        float* __restrict__ Out, int b) {
    __shared__ __align__(16) float sv[SEQ];
    __shared__ unsigned int hist[256];
    __shared__ unsigned int scn[256];
    __shared__ unsigned int swin[2];
    __shared__ float sred[4];
    __shared__ float partial[256];
    __shared__ int li[LISTCAP];
    __shared__ float wl[LISTCAP];
    __shared__ float sZ;

    const int t = threadIdx.x;
    const int i = blockIdx.x;
    const float* row = Sc + (size_t)i * SEQ;
    #pragma unroll
    for (int u = 0; u < 4; ++u) {
        int g4 = t + 256 * u;
        *(float4*)&sv[g4 * 4] = *(const float4*)&row[g4 * 4];
    }
    __syncthreads();

    // ---- exact KSP-th largest via 4x 8-bit radix select on monotone keys ----
    unsigned int prefix = 0;
    int remain = KSP;
    for (int shift = 24; shift >= 0; shift -= 8) {
        hist[t] = 0;
        __syncthreads();
        for (int u = 0; u < 16; ++u) {
            unsigned int key = fkey(sv[t + 256 * u]);
            bool ok = (shift == 24) || (((key ^ prefix) >> (shift + 8)) == 0);
            if (ok) atomicAdd(&hist[(key >> shift) & 255], 1u);
        }
        __syncthreads();
        scn[t] = hist[255 - t];
        __syncthreads();
        for (int off = 1; off < 256; off <<= 1) {
            unsigned int add = (t >= off) ? scn[t - off] : 0u;
            __syncthreads();
            scn[t] += add;
            __syncthreads();
        }
        unsigned int cg  = scn[255 - t];                       // count of digit >= t
        unsigned int cgt = (t == 255) ? 0u : scn[254 - t];     // count of digit >  t
        if (cg >= (unsigned)remain && cgt < (unsigned)remain) {
            swin[0] = (unsigned)t;
            swin[1] = cgt;
        }
        __syncthreads();
        prefix |= swin[0] << shift;
        remain -= (int)swin[1];
        __syncthreads();
    }
    const unsigned int thrk = prefix;   // exact key of the KSP-th largest score

    // ---- row max ----
    float lm = -INFINITY;
    for (int u = 0; u < 16; ++u) lm = fmaxf(lm, sv[t + 256 * u]);
    #pragma unroll
    for (int o = 32; o >= 1; o >>= 1) lm = fmaxf(lm, __shfl_xor(lm, o));
    if ((t & 63) == 0) sred[t >> 6] = lm;
    __syncthreads();
    const float m = fmaxf(fmaxf(sred[0], sred[1]), fmaxf(sred[2], sred[3]));

    // ---- deterministic compaction of selected (key >= thrk) ----
    int mycnt = 0;
    for (int u = 0; u < 16; ++u)
        if (fkey(sv[t + 256 * u]) >= thrk) mycnt++;
    scn[t] = (unsigned)mycnt;
    __syncthreads();
    for (int off = 1; off < 256; off <<= 1) {
        unsigned int add = (t >= off) ? scn[t - off] : 0u;
        __syncthreads();
        scn[t] += add;
        __syncthreads();
    }
    int off = (int)scn[t] - mycnt;      // exclusive offset
    const int cnt = (int)scn[255];
    float lsum = 0.0f;
    for (int u = 0; u < 16; ++u) {
        int j = t + 256 * u;
        float s = sv[j];
        if (fkey(s) >= thrk) {
            float w = __expf(s - m);
            if (off < LISTCAP) { li[off] = j; wl[off] = w; }
            off++;
            lsum += w;
        }
    }
    #pragma unroll
    for (int o = 32; o >= 1; o >>= 1) lsum += __shfl_xor(lsum, o);
    if ((t & 63) == 0) sred[t >> 6] = lsum;
    __syncthreads();
    if (t == 0) sZ = sred[0] + sred[1] + sred[2] + sred[3];
    __syncthreads();
    const float Zinv = 1.0f / sZ;

    // ---- P.V : wave g handles list entries n = g, g+4, ...; lane d = output dim ----
    const int d = t & 63;
    const int g = t >> 6;
    const float* vbase = QKV + (size_t)b * SEQ * EE + 128;   // v = qkv[..., 128:192]
    const int cc = cnt < LISTCAP ? cnt : LISTCAP;
    float acc = 0.0f;
    for (int n = g; n < cc; n += 4) {
        int j = li[n];
        float w = wl[n];
        acc = fmaf(w, vbase[(size_t)j * EE + d], acc);
    }
    partial[t] = acc;
    __syncthreads();
    if (t < 64) {
        float o = (partial[d] + partial[64 + d] + partial[128 + d] + partial[192 + d]) * Zinv;
        Out[((size_t)b * SEQ + i) * HD + d] = o;
    }
}

extern "C" void kernel_launch(void* const* d_in, const int* in_sizes, int n_in,
                              void* d_out, int out_size, void* d_ws, size_t ws_size,
                              hipStream_t stream) {
    (void)in_sizes; (void)n_in; (void)out_size; (void)ws_size;
    const float* X = (const float*)d_in[0];       // [4,4096,1024]
    const float* W = (const float*)d_in[1];       // [192,1024]
    float* Out = (float*)d_out;                   // [4,4096,64]
    float* qkv = (float*)d_ws;                                        // 12.6 MB
    float* sc  = (float*)((char*)d_ws + (size_t)BATCH * SEQ * EE * 4); // 64 MB (per-batch reuse)

    qkv_kernel<<<dim3(256, 3), 256, 0, stream>>>(X, W, qkv);
    for (int b = 0; b < BATCH; ++b) {
        scores_kernel<<<dim3(32, 32), 256, 0, stream>>>(qkv, sc, b);
        topk_attn_kernel<<<SEQ, 256, 0, stream>>>(qkv, sc, Out, b);
    }
}

// Round 2
// 605.762 us; speedup vs baseline: 1.3247x; 1.3247x over previous
//
#include <hip/hip_runtime.h>
#include <math.h>

#define BATCH 4
#define SEQ 4096
#define DMODEL 1024
#define HD 64
#define EE 192          // 3*HD
#define KSP 409         // max(1, int(4096*0.1))
#define SCALE 0.125f
#define LISTCAP 512

__device__ __forceinline__ unsigned int fkey(float f) {
    unsigned int u = __float_as_uint(f);
    return (u & 0x80000000u) ? ~u : (u | 0x80000000u);
}
__device__ __forceinline__ float ikey(unsigned int k) {
    unsigned int u = (k & 0x80000000u) ? (k ^ 0x80000000u) : ~k;
    return __uint_as_float(u);
}

// ---------------- K1: QKV projection  qkv[m][e] = X[m][:] . W[e][:] ----------------
__global__ __launch_bounds__(256) void qkv_kernel(const float* __restrict__ X,
                                                  const float* __restrict__ W,
                                                  float* __restrict__ QKV) {
    __shared__ __align__(16) float Xs[16][68];
    __shared__ __align__(16) float Ws[16][68];
    const int t = threadIdx.x;
    const int m0 = blockIdx.x * 64;
    const int n0 = blockIdx.y * 64;
    const int ma = (t & 15) * 4;
    const int na = (t >> 4) * 4;
    const int lr = t >> 2;
    const int lc = (t & 3) * 4;
    float acc[4][4] = {};
    for (int k0 = 0; k0 < DMODEL; k0 += 16) {
        __syncthreads();
        float4 xv = *(const float4*)&X[(size_t)(m0 + lr) * DMODEL + k0 + lc];
        Xs[lc + 0][lr] = xv.x; Xs[lc + 1][lr] = xv.y; Xs[lc + 2][lr] = xv.z; Xs[lc + 3][lr] = xv.w;
        float4 wv = *(const float4*)&W[(size_t)(n0 + lr) * DMODEL + k0 + lc];
        Ws[lc + 0][lr] = wv.x; Ws[lc + 1][lr] = wv.y; Ws[lc + 2][lr] = wv.z; Ws[lc + 3][lr] = wv.w;
        __syncthreads();
        #pragma unroll
        for (int kk = 0; kk < 16; ++kk) {
            float4 a4 = *(const float4*)&Xs[kk][ma];
            float4 b4 = *(const float4*)&Ws[kk][na];
            float a[4] = {a4.x, a4.y, a4.z, a4.w};
            float b[4] = {b4.x, b4.y, b4.z, b4.w};
            #pragma unroll
            for (int i = 0; i < 4; ++i)
                #pragma unroll
                for (int j = 0; j < 4; ++j)
                    acc[i][j] = fmaf(a[i], b[j], acc[i][j]);
        }
    }
    #pragma unroll
    for (int i = 0; i < 4; ++i) {
        float4 o = {acc[i][0], acc[i][1], acc[i][2], acc[i][3]};
        *(float4*)&QKV[(size_t)(m0 + ma + i) * EE + n0 + na] = o;
    }
}

// ---------------- K2: scores for one batch: S[i][j] = SCALE * q_i . k_j ----------------
__global__ __launch_bounds__(256) void scores_kernel(const float* __restrict__ QKV,
                                                     float* __restrict__ Sc, int b) {
    __shared__ __align__(16) float Qs[64][128];
    __shared__ __align__(16) float Ks[64][128];
    const int t = threadIdx.x;
    const int i0 = blockIdx.y * 128;
    const int j0 = blockIdx.x * 128;
    const float* base = QKV + (size_t)b * SEQ * EE;
    #pragma unroll
    for (int u = 0; u < 8; ++u) {
        int g4 = t + 256 * u;
        int r  = g4 >> 4;
        int c  = (g4 & 15) * 4;
        float4 qv = *(const float4*)&base[(size_t)(i0 + r) * EE + c];
        Qs[c + 0][r] = qv.x; Qs[c + 1][r] = qv.y; Qs[c + 2][r] = qv.z; Qs[c + 3][r] = qv.w;
        float4 kv = *(const float4*)&base[(size_t)(j0 + r) * EE + 64 + c];
        Ks[c + 0][r] = kv.x; Ks[c + 1][r] = kv.y; Ks[c + 2][r] = kv.z; Ks[c + 3][r] = kv.w;
    }
    __syncthreads();
    float acc[8][8] = {};
    const int ma = (t & 15) * 8;
    const int na = (t >> 4) * 8;
    #pragma unroll 4
    for (int kk = 0; kk < 64; ++kk) {
        float4 a0 = *(const float4*)&Qs[kk][ma];
        float4 a1 = *(const float4*)&Qs[kk][ma + 4];
        float4 b0 = *(const float4*)&Ks[kk][na];
        float4 b1 = *(const float4*)&Ks[kk][na + 4];
        float a[8] = {a0.x, a0.y, a0.z, a0.w, a1.x, a1.y, a1.z, a1.w};
        float bb[8] = {b0.x, b0.y, b0.z, b0.w, b1.x, b1.y, b1.z, b1.w};
        #pragma unroll
        for (int i = 0; i < 8; ++i)
            #pragma unroll
            for (int j = 0; j < 8; ++j)
                acc[i][j] = fmaf(a[i], bb[j], acc[i][j]);
    }
    #pragma unroll
    for (int i = 0; i < 8; ++i) {
        float* orow = Sc + (size_t)(i0 + ma + i) * SEQ + j0 + na;
        float4 o0 = {acc[i][0] * SCALE, acc[i][1] * SCALE, acc[i][2] * SCALE, acc[i][3] * SCALE};
        float4 o1 = {acc[i][4] * SCALE, acc[i][5] * SCALE, acc[i][6] * SCALE, acc[i][7] * SCALE};
        *(float4*)&orow[0] = o0;
        *(float4*)&orow[4] = o1;
    }
}

// ---------------- K3: per-row exact top-K select + softmax + P.V (register keys) ----------------
__global__ __launch_bounds__(256) void topk_attn_kernel(const float* __restrict__ QKV,
                                                        const float* __restrict__ Sc,
                                                        float* __restrict__ Out, int b) {
    __shared__ unsigned int hist[4][256];   // wave-private histograms
    __shared__ unsigned int wsum[4];
    __shared__ unsigned int swin[2];
    __shared__ unsigned int smax[4];
    __shared__ float sredf[4];
    __shared__ float partial[256];
    __shared__ int li[LISTCAP];
    __shared__ float wl[LISTCAP];
    __shared__ float sZ;

    const int t = threadIdx.x;
    const int lane = t & 63;
    const int wv = t >> 6;
    const unsigned long long ltmask = (1ull << lane) - 1ull;

    // ---- load 16 scores/thread straight into register keys ----
    // slot su (0..15): u = su>>2 (float4 index), c = su&3 ; j = u*1024 + t*4 + c
    const float* row = Sc + (size_t)blockIdx.x * SEQ;
    unsigned int key[16];
    #pragma unroll
    for (int u = 0; u < 4; ++u) {
        float4 v4 = *(const float4*)&row[u * 1024 + t * 4];
        key[u * 4 + 0] = fkey(v4.x);
        key[u * 4 + 1] = fkey(v4.y);
        key[u * 4 + 2] = fkey(v4.z);
        key[u * 4 + 3] = fkey(v4.w);
    }

    // ---- exact KSP-th largest via 4x 8-bit radix select ----
    unsigned int prefix = 0;
    int remain = KSP;
    for (int shift = 24; shift >= 0; shift -= 8) {
        #pragma unroll
        for (int i = 0; i < 4; ++i) ((unsigned int*)hist)[t + 256 * i] = 0;
        __syncthreads();
        #pragma unroll
        for (int su = 0; su < 16; ++su) {
            unsigned int k = key[su];
            bool ok = (shift == 24) || (((k ^ prefix) >> (shift + 8)) == 0);
            if (ok) atomicAdd(&hist[wv][(k >> shift) & 255], 1u);
        }
        __syncthreads();
        // thread t owns descending digit d = 255 - t
        unsigned int c = hist[0][255 - t] + hist[1][255 - t] + hist[2][255 - t] + hist[3][255 - t];
        unsigned int s = c;
        #pragma unroll
        for (int off = 1; off < 64; off <<= 1) {
            unsigned int o = __shfl_up(s, off);
            if (lane >= off) s += o;
        }
        if (lane == 63) wsum[wv] = s;
        __syncthreads();
        unsigned int base = 0;
        for (int w2 = 0; w2 < wv; ++w2) base += wsum[w2];
        s += base;
        unsigned int cgt = s - c;     // count of digit strictly greater
        if (s >= (unsigned)remain && cgt < (unsigned)remain) {
            swin[0] = 255u - (unsigned)t;
            swin[1] = cgt;
        }
        __syncthreads();
        prefix |= swin[0] << shift;
        remain -= (int)swin[1];
        __syncthreads();
    }
    const unsigned int thrk = prefix;   // exact key of the KSP-th largest score

    // ---- row max (max key == max score, monotone) ----
    unsigned int mk = 0;
    #pragma unroll
    for (int su = 0; su < 16; ++su) mk = max(mk, key[su]);
    #pragma unroll
    for (int off = 32; off >= 1; off >>= 1) mk = max(mk, (unsigned int)__shfl_xor(mk, off));
    if (lane == 0) smax[wv] = mk;
    __syncthreads();
    const float m = ikey(max(max(smax[0], smax[1]), max(smax[2], smax[3])));

    // ---- compaction: pass A wave totals ----
    int mycnt = 0;
    #pragma unroll
    for (int su = 0; su < 16; ++su) mycnt += (key[su] >= thrk) ? 1 : 0;
    int wt = mycnt;
    #pragma unroll
    for (int off = 32; off >= 1; off >>= 1) wt += __shfl_xor(wt, off);
    if (lane == 0) wsum[wv] = (unsigned)wt;
    __syncthreads();
    unsigned int wbase = 0;
    for (int w2 = 0; w2 < wv; ++w2) wbase += wsum[w2];
    const unsigned int total = wsum[0] + wsum[1] + wsum[2] + wsum[3];

    // ---- pass B: ballot-offset write of (index, weight) + local sum ----
    unsigned int pos = wbase;
    float lsum = 0.0f;
    #pragma unroll
    for (int su = 0; su < 16; ++su) {
        bool pred = key[su] >= thrk;
        unsigned long long mask = __ballot(pred);
        if (pred) {
            unsigned int myoff = pos + (unsigned int)__popcll(mask & ltmask);
            float s = ikey(key[su]);
            float w = __expf(s - m);
            if (myoff < LISTCAP) { li[myoff] = (su >> 2) * 1024 + t * 4 + (su & 3); wl[myoff] = w; }
            lsum += w;
        }
        pos += (unsigned int)__popcll(mask);
    }
    #pragma unroll
    for (int off = 32; off >= 1; off >>= 1) lsum += __shfl_xor(lsum, off);
    if (lane == 0) sredf[wv] = lsum;
    __syncthreads();
    if (t == 0) sZ = sredf[0] + sredf[1] + sredf[2] + sredf[3];
    __syncthreads();
    const float Zinv = 1.0f / sZ;

    // ---- P.V : wave wv handles list entries n = wv, wv+4, ...; lane = output dim ----
    const float* vbase = QKV + (size_t)b * SEQ * EE + 128;
    const int cc = (int)(total < LISTCAP ? total : LISTCAP);
    float acc = 0.0f;
    for (int n = wv; n < cc; n += 4) {
        int j = li[n];
        float w = wl[n];
        acc = fmaf(w, vbase[(size_t)j * EE + lane], acc);
    }
    partial[t] = acc;
    __syncthreads();
    if (t < 64) {
        float o = (partial[t] + partial[64 + t] + partial[128 + t] + partial[192 + t]) * Zinv;
        Out[((size_t)b * SEQ + blockIdx.x) * HD + t] = o;
    }
}

extern "C" void kernel_launch(void* const* d_in, const int* in_sizes, int n_in,
                              void* d_out, int out_size, void* d_ws, size_t ws_size,
                              hipStream_t stream) {
    (void)in_sizes; (void)n_in; (void)out_size; (void)ws_size;
    const float* X = (const float*)d_in[0];       // [4,4096,1024]
    const float* W = (const float*)d_in[1];       // [192,1024]
    float* Out = (float*)d_out;                   // [4,4096,64]
    float* qkv = (float*)d_ws;                                         // 12.6 MB
    float* sc  = (float*)((char*)d_ws + (size_t)BATCH * SEQ * EE * 4); // 64 MB (per-batch reuse)

    qkv_kernel<<<dim3(256, 3), 256, 0, stream>>>(X, W, qkv);
    for (int b = 0; b < BATCH; ++b) {
        scores_kernel<<<dim3(32, 32), 256, 0, stream>>>(qkv, sc, b);
        topk_attn_kernel<<<SEQ, 256, 0, stream>>>(qkv, sc, Out, b);
    }
}

// Round 3
// 442.351 us; speedup vs baseline: 1.8140x; 1.3694x over previous
//
#include <hip/hip_runtime.h>
#include <math.h>

#define BATCH 4
#define SEQ 4096
#define DMODEL 1024
#define HD 64
#define EE 192          // 3*HD
#define KSP 409         // max(1, int(4096*0.1))
#define SCALE 0.125f
#define LISTCAP 512
#define INV2048 (1.0f/2048.0f)

using half8 = __attribute__((ext_vector_type(8))) _Float16;
using half4 = __attribute__((ext_vector_type(4))) _Float16;
using f32x4 = __attribute__((ext_vector_type(4))) float;

__device__ __forceinline__ unsigned int fkey(float f) {
    unsigned int u = __float_as_uint(f);
    return (u & 0x80000000u) ? ~u : (u | 0x80000000u);
}
__device__ __forceinline__ float ikey(unsigned int k) {
    unsigned int u = (k & 0x80000000u) ? (k ^ 0x80000000u) : ~k;
    return __uint_as_float(u);
}

// ---------------- K0: split W into fp16 hi/lo (lo scaled by 2^11) ----------------
__global__ __launch_bounds__(256) void wsplit_kernel(const float* __restrict__ W,
                                                     _Float16* __restrict__ Whi,
                                                     _Float16* __restrict__ Wlo) {
    int i = blockIdx.x * 1024 + threadIdx.x * 4;
    float4 w = *(const float4*)&W[i];
    float f[4] = {w.x, w.y, w.z, w.w};
    half4 hv, lv;
    #pragma unroll
    for (int j = 0; j < 4; ++j) {
        _Float16 h = (_Float16)f[j];
        hv[j] = h;
        lv[j] = (_Float16)((f[j] - (float)h) * 2048.0f);
    }
    *(half4*)&Whi[i] = hv;
    *(half4*)&Wlo[i] = lv;
}

// ---------------- K1: QKV via fp16 split-3 MFMA ----------------
// BM=64, BN=96, BK=32; 256 thr (4 waves 2x2); XOR-swizzled LDS; reg-prefetch pipeline.
// Emits: QH/QL, KH/KL (fp16 split of q,k) and V (f32).
#define AH_OFF 0
#define AL_OFF 4096
#define BH_OFF 8192
#define BL_OFF 14336

__global__ __launch_bounds__(256) void qkv_mfma_kernel(const float* __restrict__ X,
        const _Float16* __restrict__ Whi, const _Float16* __restrict__ Wlo,
        _Float16* __restrict__ QH, _Float16* __restrict__ QL,
        _Float16* __restrict__ KH, _Float16* __restrict__ KL,
        float* __restrict__ V) {
    __shared__ __align__(16) unsigned char lds[20480];
    const int t = threadIdx.x;
    const int lane = t & 63;
    const int wv = t >> 6;
    const int wr = wv >> 1, wc = wv & 1;
    const int m0 = blockIdx.x * 64;
    const int n0 = blockIdx.y * 96;

    // staging geometry
    const int ar = t >> 2;                 // A row 0..63
    const int akc = (t & 3) * 8;           // A k-elem 0,8,16,24
    const int aw_addr = ((ar * 64 + (t & 3) * 16) ^ ((ar & 7) << 4));
    const int br0 = t >> 2;                // B row 0..63
    const int bw0 = ((br0 * 64 + (t & 3) * 16) ^ ((br0 & 7) << 4));
    const int br1 = 64 + (t >> 2);         // B row 64..95 (threads t<128)
    const int bw1 = ((br1 * 64 + (t & 3) * 16) ^ ((br1 & 7) << 4));

    float4 xa, xb;
    uint4 pbh0, pbl0, pbh1, pbl1;

    #define LOADG(K0) { \
        const float* xp = X + (size_t)(m0 + ar) * DMODEL + (K0) + akc; \
        xa = *(const float4*)xp; xb = *(const float4*)(xp + 4); \
        size_t wo0 = (size_t)(n0 + br0) * DMODEL + (K0) + akc; \
        pbh0 = *(const uint4*)(Whi + wo0); pbl0 = *(const uint4*)(Wlo + wo0); \
        if (t < 128) { \
            size_t wo1 = (size_t)(n0 + br1) * DMODEL + (K0) + akc; \
            pbh1 = *(const uint4*)(Whi + wo1); pbl1 = *(const uint4*)(Wlo + wo1); \
        } }

    #define WRITE_LDS() { \
        float f[8] = {xa.x, xa.y, xa.z, xa.w, xb.x, xb.y, xb.z, xb.w}; \
        half8 hv, lv; \
        _Pragma("unroll") \
        for (int i2 = 0; i2 < 8; ++i2) { \
            _Float16 h = (_Float16)f[i2]; \
            hv[i2] = h; \
            lv[i2] = (_Float16)((f[i2] - (float)h) * 2048.0f); \
        } \
        *(half8*)(lds + AH_OFF + aw_addr) = hv; \
        *(half8*)(lds + AL_OFF + aw_addr) = lv; \
        *(uint4*)(lds + BH_OFF + bw0) = pbh0; \
        *(uint4*)(lds + BL_OFF + bw0) = pbl0; \
        if (t < 128) { \
            *(uint4*)(lds + BH_OFF + bw1) = pbh1; \
            *(uint4*)(lds + BL_OFF + bw1) = pbl1; \
        } }

    f32x4 hh[2][3], xx[2][3];
    #pragma unroll
    for (int mi = 0; mi < 2; ++mi)
        #pragma unroll
        for (int ni = 0; ni < 3; ++ni) {
            hh[mi][ni] = (f32x4){0.f, 0.f, 0.f, 0.f};
            xx[mi][ni] = (f32x4){0.f, 0.f, 0.f, 0.f};
        }

    LOADG(0);
    WRITE_LDS();
    __syncthreads();

    const int kb = (lane >> 4) << 4;   // k-byte within row: 0,16,32,48

    for (int it = 0; it < 32; ++it) {
        if (it < 31) LOADG((it + 1) * 32);

        half8 ah[2], al[2], bh[3], bl[3];
        #pragma unroll
        for (int mi = 0; mi < 2; ++mi) {
            int ra = wr * 32 + mi * 16 + (lane & 15);
            int ad = ((ra * 64 + kb) ^ ((ra & 7) << 4));
            ah[mi] = *(const half8*)(lds + AH_OFF + ad);
            al[mi] = *(const half8*)(lds + AL_OFF + ad);
        }
        #pragma unroll
        for (int ni = 0; ni < 3; ++ni) {
            int rb = wc * 48 + ni * 16 + (lane & 15);
            int bd = ((rb * 64 + kb) ^ ((rb & 7) << 4));
            bh[ni] = *(const half8*)(lds + BH_OFF + bd);
            bl[ni] = *(const half8*)(lds + BL_OFF + bd);
        }
        #pragma unroll
        for (int mi = 0; mi < 2; ++mi)
            #pragma unroll
            for (int ni = 0; ni < 3; ++ni) {
                hh[mi][ni] = __builtin_amdgcn_mfma_f32_16x16x32_f16(ah[mi], bh[ni], hh[mi][ni], 0, 0, 0);
                xx[mi][ni] = __builtin_amdgcn_mfma_f32_16x16x32_f16(ah[mi], bl[ni], xx[mi][ni], 0, 0, 0);
                xx[mi][ni] = __builtin_amdgcn_mfma_f32_16x16x32_f16(al[mi], bh[ni], xx[mi][ni], 0, 0, 0);
            }
        __syncthreads();
        if (it < 31) { WRITE_LDS(); __syncthreads(); }
    }

    // epilogue: C[row][col]: col=lane&15 (+16*ni), row=(lane>>4)*4+j (+16*mi)
    #pragma unroll
    for (int mi = 0; mi < 2; ++mi)
        #pragma unroll
        for (int ni = 0; ni < 3; ++ni) {
            int col = n0 + wc * 48 + ni * 16 + (lane & 15);
            int rowb = m0 + wr * 32 + mi * 16 + ((lane >> 4) << 2);
            #pragma unroll
            for (int j = 0; j < 4; ++j) {
                float val = hh[mi][ni][j] + xx[mi][ni][j] * INV2048;
                int row = rowb + j;
                if (col < 64) {
                    _Float16 h = (_Float16)val;
                    QH[(size_t)row * HD + col] = h;
                    QL[(size_t)row * HD + col] = (_Float16)((val - (float)h) * 2048.0f);
                } else if (col < 128) {
                    _Float16 h = (_Float16)val;
                    KH[(size_t)row * HD + (col - 64)] = h;
                    KL[(size_t)row * HD + (col - 64)] = (_Float16)((val - (float)h) * 2048.0f);
                } else {
                    V[(size_t)row * HD + (col - 128)] = val;
                }
            }
        }
}

// ---------------- K2: scores via fp16 split-3 MFMA ----------------
// Block tile 128 q-rows x 64 k-cols, K=64 (whole head dim) in LDS, no K-loop.
#define SQH_OFF 0
#define SQL_OFF 16384
#define SKH_OFF 32768
#define SKL_OFF 40960

__global__ __launch_bounds__(256) void scores_mfma_kernel(
        const _Float16* __restrict__ QH, const _Float16* __restrict__ QL,
        const _Float16* __restrict__ KH, const _Float16* __restrict__ KL,
        float* __restrict__ Sc) {
    __shared__ __align__(16) unsigned char lds[49152];
    const int t = threadIdx.x;
    const int lane = t & 63;
    const int wv = t >> 6;
    const int i0 = blockIdx.y * 128;
    const int j0 = blockIdx.x * 64;

    // stage Q: 128 rows x 128B (hi+lo); 1024 16B-chunks each
    #pragma unroll
    for (int u = 0; u < 4; ++u) {
        int ch = t + 256 * u;
        int r = ch >> 3;
        int kbyte = (ch & 7) * 16;
        int ad = (r * 128 + kbyte) ^ ((r & 7) << 4);
        *(uint4*)(lds + SQH_OFF + ad) = *(const uint4*)((const char*)QH + (size_t)(i0 + r) * 128 + kbyte);
        *(uint4*)(lds + SQL_OFF + ad) = *(const uint4*)((const char*)QL + (size_t)(i0 + r) * 128 + kbyte);
    }
    // stage K: 64 rows
    #pragma unroll
    for (int u = 0; u < 2; ++u) {
        int ch = t + 256 * u;
        int r = ch >> 3;
        int kbyte = (ch & 7) * 16;
        int ad = (r * 128 + kbyte) ^ ((r & 7) << 4);
        *(uint4*)(lds + SKH_OFF + ad) = *(const uint4*)((const char*)KH + (size_t)(j0 + r) * 128 + kbyte);
        *(uint4*)(lds + SKL_OFF + ad) = *(const uint4*)((const char*)KL + (size_t)(j0 + r) * 128 + kbyte);
    }
    __syncthreads();

    f32x4 hh[2][4], xx[2][4];
    #pragma unroll
    for (int mi = 0; mi < 2; ++mi)
        #pragma unroll
        for (int ni = 0; ni < 4; ++ni) {
            hh[mi][ni] = (f32x4){0.f, 0.f, 0.f, 0.f};
            xx[mi][ni] = (f32x4){0.f, 0.f, 0.f, 0.f};
        }

    #pragma unroll
    for (int ks = 0; ks < 2; ++ks) {
        int kbyte = ks * 64 + ((lane >> 4) << 4);
        half8 qh[2], ql[2], kh[4], kl[4];
        #pragma unroll
        for (int mi = 0; mi < 2; ++mi) {
            int r = wv * 32 + mi * 16 + (lane & 15);
            int ad = (r * 128 + kbyte) ^ ((r & 7) << 4);
            qh[mi] = *(const half8*)(lds + SQH_OFF + ad);
            ql[mi] = *(const half8*)(lds + SQL_OFF + ad);
        }
        #pragma unroll
        for (int ni = 0; ni < 4; ++ni) {
            int r = ni * 16 + (lane & 15);
            int ad = (r * 128 + kbyte) ^ ((r & 7) << 4);
            kh[ni] = *(const half8*)(lds + SKH_OFF + ad);
            kl[ni] = *(const half8*)(lds + SKL_OFF + ad);
        }
        #pragma unroll
        for (int mi = 0; mi < 2; ++mi)
            #pragma unroll
            for (int ni = 0; ni < 4; ++ni) {
                hh[mi][ni] = __builtin_amdgcn_mfma_f32_16x16x32_f16(qh[mi], kh[ni], hh[mi][ni], 0, 0, 0);
                xx[mi][ni] = __builtin_amdgcn_mfma_f32_16x16x32_f16(qh[mi], kl[ni], xx[mi][ni], 0, 0, 0);
                xx[mi][ni] = __builtin_amdgcn_mfma_f32_16x16x32_f16(ql[mi], kh[ni], xx[mi][ni], 0, 0, 0);
            }
    }

    #pragma unroll
    for (int mi = 0; mi < 2; ++mi)
        #pragma unroll
        for (int ni = 0; ni < 4; ++ni) {
            int col = j0 + ni * 16 + (lane & 15);
            int rowb = i0 + wv * 32 + mi * 16 + ((lane >> 4) << 2);
            #pragma unroll
            for (int j = 0; j < 4; ++j) {
                float s = SCALE * (hh[mi][ni][j] + xx[mi][ni][j] * INV2048);
                Sc[(size_t)(rowb + j) * SEQ + col] = s;
            }
        }
}

// ---------------- K3: per-row exact top-K select + softmax + P.V (register keys) ----------------
__global__ __launch_bounds__(256) void topk_attn_kernel(const float* __restrict__ V,
                                                        const float* __restrict__ Sc,
                                                        float* __restrict__ Out, int b) {
    __shared__ unsigned int hist[4][256];
    __shared__ unsigned int wsum[4];
    __shared__ unsigned int swin[2];
    __shared__ unsigned int smax[4];
    __shared__ float sredf[4];
    __shared__ float partial[256];
    __shared__ int li[LISTCAP];
    __shared__ float wl[LISTCAP];
    __shared__ float sZ;

    const int t = threadIdx.x;
    const int lane = t & 63;
    const int wv = t >> 6;
    const unsigned long long ltmask = (1ull << lane) - 1ull;

    const float* row = Sc + (size_t)blockIdx.x * SEQ;
    unsigned int key[16];
    #pragma unroll
    for (int u = 0; u < 4; ++u) {
        float4 v4 = *(const float4*)&row[u * 1024 + t * 4];
        key[u * 4 + 0] = fkey(v4.x);
        key[u * 4 + 1] = fkey(v4.y);
        key[u * 4 + 2] = fkey(v4.z);
        key[u * 4 + 3] = fkey(v4.w);
    }

    unsigned int prefix = 0;
    int remain = KSP;
    for (int shift = 24; shift >= 0; shift -= 8) {
        #pragma unroll
        for (int i = 0; i < 4; ++i) ((unsigned int*)hist)[t + 256 * i] = 0;
        __syncthreads();
        #pragma unroll
        for (int su = 0; su < 16; ++su) {
            unsigned int k = key[su];
            bool ok = (shift == 24) || (((k ^ prefix) >> (shift + 8)) == 0);
            if (ok) atomicAdd(&hist[wv][(k >> shift) & 255], 1u);
        }
        __syncthreads();
        unsigned int c = hist[0][255 - t] + hist[1][255 - t] + hist[2][255 - t] + hist[3][255 - t];
        unsigned int s = c;
        #pragma unroll
        for (int off = 1; off < 64; off <<= 1) {
            unsigned int o = __shfl_up(s, off);
            if (lane >= off) s += o;
        }
        if (lane == 63) wsum[wv] = s;
        __syncthreads();
        unsigned int base = 0;
        for (int w2 = 0; w2 < wv; ++w2) base += wsum[w2];
        s += base;
        unsigned int cgt = s - c;
        if (s >= (unsigned)remain && cgt < (unsigned)remain) {
            swin[0] = 255u - (unsigned)t;
            swin[1] = cgt;
        }
        __syncthreads();
        prefix |= swin[0] << shift;
        remain -= (int)swin[1];
        __syncthreads();
    }
    const unsigned int thrk = prefix;

    unsigned int mk = 0;
    #pragma unroll
    for (int su = 0; su < 16; ++su) mk = max(mk, key[su]);
    #pragma unroll
    for (int off = 32; off >= 1; off >>= 1) mk = max(mk, (unsigned int)__shfl_xor(mk, off));
    if (lane == 0) smax[wv] = mk;
    __syncthreads();
    const float m = ikey(max(max(smax[0], smax[1]), max(smax[2], smax[3])));

    int mycnt = 0;
    #pragma unroll
    for (int su = 0; su < 16; ++su) mycnt += (key[su] >= thrk) ? 1 : 0;
    int wt = mycnt;
    #pragma unroll
    for (int off = 32; off >= 1; off >>= 1) wt += __shfl_xor(wt, off);
    if (lane == 0) wsum[wv] = (unsigned)wt;
    __syncthreads();
    unsigned int wbase = 0;
    for (int w2 = 0; w2 < wv; ++w2) wbase += wsum[w2];
    const unsigned int total = wsum[0] + wsum[1] + wsum[2] + wsum[3];

    unsigned int pos = wbase;
    float lsum = 0.0f;
    #pragma unroll
    for (int su = 0; su < 16; ++su) {
        bool pred = key[su] >= thrk;
        unsigned long long mask = __ballot(pred);
        if (pred) {
            unsigned int myoff = pos + (unsigned int)__popcll(mask & ltmask);
            float s = ikey(key[su]);
            float w = __expf(s - m);
            if (myoff < LISTCAP) { li[myoff] = (su >> 2) * 1024 + t * 4 + (su & 3); wl[myoff] = w; }
            lsum += w;
        }
        pos += (unsigned int)__popcll(mask);
    }
    #pragma unroll
    for (int off = 32; off >= 1; off >>= 1) lsum += __shfl_xor(lsum, off);
    if (lane == 0) sredf[wv] = lsum;
    __syncthreads();
    if (t == 0) sZ = sredf[0] + sredf[1] + sredf[2] + sredf[3];
    __syncthreads();
    const float Zinv = 1.0f / sZ;

    const float* vbase = V + (size_t)b * SEQ * HD;
    const int cc = (int)(total < LISTCAP ? total : LISTCAP);
    float acc = 0.0f;
    for (int n = wv; n < cc; n += 4) {
        int j = li[n];
        float w = wl[n];
        acc = fmaf(w, vbase[(size_t)j * HD + lane], acc);
    }
    partial[t] = acc;
    __syncthreads();
    if (t < 64) {
        float o = (partial[t] + partial[64 + t] + partial[128 + t] + partial[192 + t]) * Zinv;
        Out[((size_t)b * SEQ + blockIdx.x) * HD + t] = o;
    }
}

extern "C" void kernel_launch(void* const* d_in, const int* in_sizes, int n_in,
                              void* d_out, int out_size, void* d_ws, size_t ws_size,
                              hipStream_t stream) {
    (void)in_sizes; (void)n_in; (void)out_size; (void)ws_size;
    const float* X = (const float*)d_in[0];       // [4,4096,1024]
    const float* W = (const float*)d_in[1];       // [192,1024]
    float* Out = (float*)d_out;                   // [4,4096,64]

    char* ws = (char*)d_ws;
    const size_t V_BYTES  = (size_t)BATCH * SEQ * HD * 4;     //  4.2 MB
    const size_t SC_BYTES = (size_t)SEQ * SEQ * 4;            // 67.1 MB (per-batch reuse)
    const size_t WH_BYTES = (size_t)EE * DMODEL * 2;          //  0.39 MB
    const size_t QH_BYTES = (size_t)BATCH * SEQ * HD * 2;     //  2.1 MB

    float*    Vv  = (float*)(ws);
    float*    sc  = (float*)(ws + V_BYTES);
    _Float16* Whi = (_Float16*)(ws + V_BYTES + SC_BYTES);
    _Float16* Wlo = (_Float16*)(ws + V_BYTES + SC_BYTES + WH_BYTES);
    _Float16* QH  = (_Float16*)(ws + V_BYTES + SC_BYTES + 2 * WH_BYTES);
    _Float16* QL  = (_Float16*)(ws + V_BYTES + SC_BYTES + 2 * WH_BYTES + QH_BYTES);
    _Float16* KH  = (_Float16*)(ws + V_BYTES + SC_BYTES + 2 * WH_BYTES + 2 * QH_BYTES);
    _Float16* KL  = (_Float16*)(ws + V_BYTES + SC_BYTES + 2 * WH_BYTES + 3 * QH_BYTES);

    wsplit_kernel<<<EE, 256, 0, stream>>>(W, Whi, Wlo);
    qkv_mfma_kernel<<<dim3(256, 2), 256, 0, stream>>>(X, Whi, Wlo, QH, QL, KH, KL, Vv);
    for (int b = 0; b < BATCH; ++b) {
        scores_mfma_kernel<<<dim3(64, 32), 256, 0, stream>>>(
            QH + (size_t)b * SEQ * HD, QL + (size_t)b * SEQ * HD,
            KH + (size_t)b * SEQ * HD, KL + (size_t)b * SEQ * HD, sc);
        topk_attn_kernel<<<SEQ, 256, 0, stream>>>(Vv, sc, Out, b);
    }
}

// Round 4
// 315.155 us; speedup vs baseline: 2.5462x; 1.4036x over previous
//
#include <hip/hip_runtime.h>
#include <math.h>

#define BATCH 4
#define SEQ 4096
#define DMODEL 1024
#define HD 64
#define EE 192          // 3*HD
#define KSP 409         // max(1, int(4096*0.1))
#define SCALE 0.125f
#define LISTCAP 512
#define INV2048 (1.0f/2048.0f)

using half8 = __attribute__((ext_vector_type(8))) _Float16;
using half4 = __attribute__((ext_vector_type(4))) _Float16;
using f32x4 = __attribute__((ext_vector_type(4))) float;

__device__ __forceinline__ unsigned int fkey(float f) {
    unsigned int u = __float_as_uint(f);
    return (u & 0x80000000u) ? ~u : (u | 0x80000000u);
}
__device__ __forceinline__ float ikey(unsigned int k) {
    unsigned int u = (k & 0x80000000u) ? (k ^ 0x80000000u) : ~k;
    return __uint_as_float(u);
}

// ---------------- K0: split W into fp16 hi/lo (lo scaled by 2^11) ----------------
__global__ __launch_bounds__(256) void wsplit_kernel(const float* __restrict__ W,
                                                     _Float16* __restrict__ Whi,
                                                     _Float16* __restrict__ Wlo) {
    int i = blockIdx.x * 1024 + threadIdx.x * 4;
    float4 w = *(const float4*)&W[i];
    float f[4] = {w.x, w.y, w.z, w.w};
    half4 hv, lv;
    #pragma unroll
    for (int j = 0; j < 4; ++j) {
        _Float16 h = (_Float16)f[j];
        hv[j] = h;
        lv[j] = (_Float16)((f[j] - (float)h) * 2048.0f);
    }
    *(half4*)&Whi[i] = hv;
    *(half4*)&Wlo[i] = lv;
}

// ---------------- K1: QKV via fp16 split-3 MFMA ----------------
#define AH_OFF 0
#define AL_OFF 4096
#define BH_OFF 8192
#define BL_OFF 14336

__global__ __launch_bounds__(256) void qkv_mfma_kernel(const float* __restrict__ X,
        const _Float16* __restrict__ Whi, const _Float16* __restrict__ Wlo,
        _Float16* __restrict__ QH, _Float16* __restrict__ QL,
        _Float16* __restrict__ KH, _Float16* __restrict__ KL,
        float* __restrict__ V) {
    __shared__ __align__(16) unsigned char lds[20480];
    const int t = threadIdx.x;
    const int lane = t & 63;
    const int wv = t >> 6;
    const int wr = wv >> 1, wc = wv & 1;
    const int m0 = blockIdx.x * 64;
    const int n0 = blockIdx.y * 96;

    const int ar = t >> 2;
    const int akc = (t & 3) * 8;
    const int aw_addr = ((ar * 64 + (t & 3) * 16) ^ ((ar & 7) << 4));
    const int br0 = t >> 2;
    const int bw0 = ((br0 * 64 + (t & 3) * 16) ^ ((br0 & 7) << 4));
    const int br1 = 64 + (t >> 2);
    const int bw1 = ((br1 * 64 + (t & 3) * 16) ^ ((br1 & 7) << 4));

    float4 xa, xb;
    uint4 pbh0, pbl0, pbh1, pbl1;

    #define LOADG(K0) { \
        const float* xp = X + (size_t)(m0 + ar) * DMODEL + (K0) + akc; \
        xa = *(const float4*)xp; xb = *(const float4*)(xp + 4); \
        size_t wo0 = (size_t)(n0 + br0) * DMODEL + (K0) + akc; \
        pbh0 = *(const uint4*)(Whi + wo0); pbl0 = *(const uint4*)(Wlo + wo0); \
        if (t < 128) { \
            size_t wo1 = (size_t)(n0 + br1) * DMODEL + (K0) + akc; \
            pbh1 = *(const uint4*)(Whi + wo1); pbl1 = *(const uint4*)(Wlo + wo1); \
        } }

    #define WRITE_LDS() { \
        float f[8] = {xa.x, xa.y, xa.z, xa.w, xb.x, xb.y, xb.z, xb.w}; \
        half8 hv, lv; \
        _Pragma("unroll") \
        for (int i2 = 0; i2 < 8; ++i2) { \
            _Float16 h = (_Float16)f[i2]; \
            hv[i2] = h; \
            lv[i2] = (_Float16)((f[i2] - (float)h) * 2048.0f); \
        } \
        *(half8*)(lds + AH_OFF + aw_addr) = hv; \
        *(half8*)(lds + AL_OFF + aw_addr) = lv; \
        *(uint4*)(lds + BH_OFF + bw0) = pbh0; \
        *(uint4*)(lds + BL_OFF + bw0) = pbl0; \
        if (t < 128) { \
            *(uint4*)(lds + BH_OFF + bw1) = pbh1; \
            *(uint4*)(lds + BL_OFF + bw1) = pbl1; \
        } }

    f32x4 hh[2][3], xx[2][3];
    #pragma unroll
    for (int mi = 0; mi < 2; ++mi)
        #pragma unroll
        for (int ni = 0; ni < 3; ++ni) {
            hh[mi][ni] = (f32x4){0.f, 0.f, 0.f, 0.f};
            xx[mi][ni] = (f32x4){0.f, 0.f, 0.f, 0.f};
        }

    LOADG(0);
    WRITE_LDS();
    __syncthreads();

    const int kb = (lane >> 4) << 4;

    for (int it = 0; it < 32; ++it) {
        if (it < 31) LOADG((it + 1) * 32);

        half8 ah[2], al[2], bh[3], bl[3];
        #pragma unroll
        for (int mi = 0; mi < 2; ++mi) {
            int ra = wr * 32 + mi * 16 + (lane & 15);
            int ad = ((ra * 64 + kb) ^ ((ra & 7) << 4));
            ah[mi] = *(const half8*)(lds + AH_OFF + ad);
            al[mi] = *(const half8*)(lds + AL_OFF + ad);
        }
        #pragma unroll
        for (int ni = 0; ni < 3; ++ni) {
            int rb = wc * 48 + ni * 16 + (lane & 15);
            int bd = ((rb * 64 + kb) ^ ((rb & 7) << 4));
            bh[ni] = *(const half8*)(lds + BH_OFF + bd);
            bl[ni] = *(const half8*)(lds + BL_OFF + bd);
        }
        #pragma unroll
        for (int mi = 0; mi < 2; ++mi)
            #pragma unroll
            for (int ni = 0; ni < 3; ++ni) {
                hh[mi][ni] = __builtin_amdgcn_mfma_f32_16x16x32_f16(ah[mi], bh[ni], hh[mi][ni], 0, 0, 0);
                xx[mi][ni] = __builtin_amdgcn_mfma_f32_16x16x32_f16(ah[mi], bl[ni], xx[mi][ni], 0, 0, 0);
                xx[mi][ni] = __builtin_amdgcn_mfma_f32_16x16x32_f16(al[mi], bh[ni], xx[mi][ni], 0, 0, 0);
            }
        __syncthreads();
        if (it < 31) { WRITE_LDS(); __syncthreads(); }
    }

    #pragma unroll
    for (int mi = 0; mi < 2; ++mi)
        #pragma unroll
        for (int ni = 0; ni < 3; ++ni) {
            int col = n0 + wc * 48 + ni * 16 + (lane & 15);
            int rowb = m0 + wr * 32 + mi * 16 + ((lane >> 4) << 2);
            #pragma unroll
            for (int j = 0; j < 4; ++j) {
                float val = hh[mi][ni][j] + xx[mi][ni][j] * INV2048;
                int row = rowb + j;
                if (col < 64) {
                    _Float16 h = (_Float16)val;
                    QH[(size_t)row * HD + col] = h;
                    QL[(size_t)row * HD + col] = (_Float16)((val - (float)h) * 2048.0f);
                } else if (col < 128) {
                    _Float16 h = (_Float16)val;
                    KH[(size_t)row * HD + (col - 64)] = h;
                    KL[(size_t)row * HD + (col - 64)] = (_Float16)((val - (float)h) * 2048.0f);
                } else {
                    V[(size_t)row * HD + (col - 128)] = val;
                }
            }
        }
}

// ---------------- K2: scores via fp16 split-3 MFMA ----------------
#define SQH_OFF 0
#define SQL_OFF 16384
#define SKH_OFF 32768
#define SKL_OFF 40960

__global__ __launch_bounds__(256) void scores_mfma_kernel(
        const _Float16* __restrict__ QH, const _Float16* __restrict__ QL,
        const _Float16* __restrict__ KH, const _Float16* __restrict__ KL,
        float* __restrict__ Sc) {
    __shared__ __align__(16) unsigned char lds[49152];
    const int t = threadIdx.x;
    const int lane = t & 63;
    const int wv = t >> 6;
    const int i0 = blockIdx.y * 128;
    const int j0 = blockIdx.x * 64;

    #pragma unroll
    for (int u = 0; u < 4; ++u) {
        int ch = t + 256 * u;
        int r = ch >> 3;
        int kbyte = (ch & 7) * 16;
        int ad = (r * 128 + kbyte) ^ ((r & 7) << 4);
        *(uint4*)(lds + SQH_OFF + ad) = *(const uint4*)((const char*)QH + (size_t)(i0 + r) * 128 + kbyte);
        *(uint4*)(lds + SQL_OFF + ad) = *(const uint4*)((const char*)QL + (size_t)(i0 + r) * 128 + kbyte);
    }
    #pragma unroll
    for (int u = 0; u < 2; ++u) {
        int ch = t + 256 * u;
        int r = ch >> 3;
        int kbyte = (ch & 7) * 16;
        int ad = (r * 128 + kbyte) ^ ((r & 7) << 4);
        *(uint4*)(lds + SKH_OFF + ad) = *(const uint4*)((const char*)KH + (size_t)(j0 + r) * 128 + kbyte);
        *(uint4*)(lds + SKL_OFF + ad) = *(const uint4*)((const char*)KL + (size_t)(j0 + r) * 128 + kbyte);
    }
    __syncthreads();

    f32x4 hh[2][4], xx[2][4];
    #pragma unroll
    for (int mi = 0; mi < 2; ++mi)
        #pragma unroll
        for (int ni = 0; ni < 4; ++ni) {
            hh[mi][ni] = (f32x4){0.f, 0.f, 0.f, 0.f};
            xx[mi][ni] = (f32x4){0.f, 0.f, 0.f, 0.f};
        }

    #pragma unroll
    for (int ks = 0; ks < 2; ++ks) {
        int kbyte = ks * 64 + ((lane >> 4) << 4);
        half8 qh[2], ql[2], kh[4], kl[4];
        #pragma unroll
        for (int mi = 0; mi < 2; ++mi) {
            int r = wv * 32 + mi * 16 + (lane & 15);
            int ad = (r * 128 + kbyte) ^ ((r & 7) << 4);
            qh[mi] = *(const half8*)(lds + SQH_OFF + ad);
            ql[mi] = *(const half8*)(lds + SQL_OFF + ad);
        }
        #pragma unroll
        for (int ni = 0; ni < 4; ++ni) {
            int r = ni * 16 + (lane & 15);
            int ad = (r * 128 + kbyte) ^ ((r & 7) << 4);
            kh[ni] = *(const half8*)(lds + SKH_OFF + ad);
            kl[ni] = *(const half8*)(lds + SKL_OFF + ad);
        }
        #pragma unroll
        for (int mi = 0; mi < 2; ++mi)
            #pragma unroll
            for (int ni = 0; ni < 4; ++ni) {
                hh[mi][ni] = __builtin_amdgcn_mfma_f32_16x16x32_f16(qh[mi], kh[ni], hh[mi][ni], 0, 0, 0);
                xx[mi][ni] = __builtin_amdgcn_mfma_f32_16x16x32_f16(qh[mi], kl[ni], xx[mi][ni], 0, 0, 0);
                xx[mi][ni] = __builtin_amdgcn_mfma_f32_16x16x32_f16(ql[mi], kh[ni], xx[mi][ni], 0, 0, 0);
            }
    }

    #pragma unroll
    for (int mi = 0; mi < 2; ++mi)
        #pragma unroll
        for (int ni = 0; ni < 4; ++ni) {
            int col = j0 + ni * 16 + (lane & 15);
            int rowb = i0 + wv * 32 + mi * 16 + ((lane >> 4) << 2);
            #pragma unroll
            for (int j = 0; j < 4; ++j) {
                float s = SCALE * (hh[mi][ni][j] + xx[mi][ni][j] * INV2048);
                Sc[(size_t)(rowb + j) * SEQ + col] = s;
            }
        }
}

// ---------------- K3: per-row exact top-K select + softmax + P.V ----------------
__global__ __launch_bounds__(256) void topk_attn_kernel(const float* __restrict__ V,
                                                        const float* __restrict__ Sc,
                                                        float* __restrict__ Out, int b) {
    __shared__ unsigned int hist[4][256];
    __shared__ unsigned int wsum[4];
    __shared__ unsigned int swin[2];
    __shared__ unsigned int smax[4];
    __shared__ float sredf[4];
    __shared__ uint2 lw[LISTCAP];          // (index, weight-bits) packed
    __shared__ float pvred[4][4][64];      // [wave][group][dim]
    __shared__ float sZ;

    const int t = threadIdx.x;
    const int lane = t & 63;
    const int wv = t >> 6;
    const unsigned long long ltmask = (1ull << lane) - 1ull;

    const float* row = Sc + (size_t)blockIdx.x * SEQ;
    unsigned int key[16];
    #pragma unroll
    for (int u = 0; u < 4; ++u) {
        float4 v4 = *(const float4*)&row[u * 1024 + t * 4];
        key[u * 4 + 0] = fkey(v4.x);
        key[u * 4 + 1] = fkey(v4.y);
        key[u * 4 + 2] = fkey(v4.z);
        key[u * 4 + 3] = fkey(v4.w);
    }

    // ---- exact KSP-th largest via 4x 8-bit radix select ----
    unsigned int prefix = 0;
    int remain = KSP;
    for (int shift = 24; shift >= 0; shift -= 8) {
        #pragma unroll
        for (int i = 0; i < 4; ++i) ((unsigned int*)hist)[t + 256 * i] = 0;
        __syncthreads();
        #pragma unroll
        for (int su = 0; su < 16; ++su) {
            unsigned int k = key[su];
            bool ok = (shift == 24) || (((k ^ prefix) >> (shift + 8)) == 0);
            if (ok) atomicAdd(&hist[wv][(k >> shift) & 255], 1u);
        }
        __syncthreads();
        unsigned int c = hist[0][255 - t] + hist[1][255 - t] + hist[2][255 - t] + hist[3][255 - t];
        unsigned int s = c;
        #pragma unroll
        for (int off = 1; off < 64; off <<= 1) {
            unsigned int o = __shfl_up(s, off);
            if (lane >= off) s += o;
        }
        if (lane == 63) wsum[wv] = s;
        __syncthreads();
        unsigned int base = 0;
        for (int w2 = 0; w2 < wv; ++w2) base += wsum[w2];
        s += base;
        unsigned int cgt = s - c;
        if (s >= (unsigned)remain && cgt < (unsigned)remain) {
            swin[0] = 255u - (unsigned)t;
            swin[1] = cgt;
        }
        __syncthreads();
        prefix |= swin[0] << shift;
        remain -= (int)swin[1];
        __syncthreads();
    }
    const unsigned int thrk = prefix;

    // ---- row max ----
    unsigned int mk = 0;
    #pragma unroll
    for (int su = 0; su < 16; ++su) mk = max(mk, key[su]);
    #pragma unroll
    for (int off = 32; off >= 1; off >>= 1) mk = max(mk, (unsigned int)__shfl_xor(mk, off));
    if (lane == 0) smax[wv] = mk;
    __syncthreads();
    const float m = ikey(max(max(smax[0], smax[1]), max(smax[2], smax[3])));

    // ---- compaction: ballot once, reuse masks ----
    unsigned long long msk[16];
    unsigned int wt = 0;
    #pragma unroll
    for (int su = 0; su < 16; ++su) {
        msk[su] = __ballot(key[su] >= thrk);
        wt += (unsigned int)__popcll(msk[su]);
    }
    if (lane == 0) wsum[wv] = wt;
    __syncthreads();
    unsigned int wbase = 0;
    for (int w2 = 0; w2 < wv; ++w2) wbase += wsum[w2];
    const unsigned int total = wsum[0] + wsum[1] + wsum[2] + wsum[3];

    unsigned int pos = wbase;
    float lsum = 0.0f;
    #pragma unroll
    for (int su = 0; su < 16; ++su) {
        if (key[su] >= thrk) {
            unsigned int myoff = pos + (unsigned int)__popcll(msk[su] & ltmask);
            float s = ikey(key[su]);
            float w = __expf(s - m);
            if (myoff < LISTCAP) {
                lw[myoff] = make_uint2((unsigned)((su >> 2) * 1024 + t * 4 + (su & 3)),
                                       __float_as_uint(w));
            }
            lsum += w;
        }
        pos += (unsigned int)__popcll(msk[su]);
    }
    #pragma unroll
    for (int off = 32; off >= 1; off >>= 1) lsum += __shfl_xor(lsum, off);
    if (lane == 0) sredf[wv] = lsum;
    __syncthreads();
    if (t == 0) sZ = sredf[0] + sredf[1] + sredf[2] + sredf[3];
    __syncthreads();
    const float Zinv = 1.0f / sZ;

    // ---- P.V : 16 entries per block-iter; lane = 16*g + q, q holds dims 4q..4q+3 ----
    const int q = lane & 15;
    const int g = lane >> 4;
    const int cc = (int)(total < LISTCAP ? total : LISTCAP);
    const float* vbase = V + (size_t)b * SEQ * HD + 4 * q;
    float a0 = 0.f, a1 = 0.f, a2 = 0.f, a3 = 0.f;
    #pragma unroll 2
    for (int n = wv * 4 + g; n < cc; n += 16) {
        uint2 e = lw[n];
        float w = __uint_as_float(e.y);
        float4 v4 = *(const float4*)(vbase + (size_t)e.x * HD);
        a0 = fmaf(w, v4.x, a0);
        a1 = fmaf(w, v4.y, a1);
        a2 = fmaf(w, v4.z, a2);
        a3 = fmaf(w, v4.w, a3);
    }
    pvred[wv][g][4 * q + 0] = a0;
    pvred[wv][g][4 * q + 1] = a1;
    pvred[wv][g][4 * q + 2] = a2;
    pvred[wv][g][4 * q + 3] = a3;
    __syncthreads();
    if (t < 64) {
        float o = 0.f;
        #pragma unroll
        for (int w2 = 0; w2 < 4; ++w2)
            #pragma unroll
            for (int g2 = 0; g2 < 4; ++g2)
                o += pvred[w2][g2][t];
        Out[((size_t)b * SEQ + blockIdx.x) * HD + t] = o * Zinv;
    }
}

extern "C" void kernel_launch(void* const* d_in, const int* in_sizes, int n_in,
                              void* d_out, int out_size, void* d_ws, size_t ws_size,
                              hipStream_t stream) {
    (void)in_sizes; (void)n_in; (void)out_size; (void)ws_size;
    const float* X = (const float*)d_in[0];       // [4,4096,1024]
    const float* W = (const float*)d_in[1];       // [192,1024]
    float* Out = (float*)d_out;                   // [4,4096,64]

    char* ws = (char*)d_ws;
    const size_t V_BYTES  = (size_t)BATCH * SEQ * HD * 4;
    const size_t SC_BYTES = (size_t)SEQ * SEQ * 4;
    const size_t WH_BYTES = (size_t)EE * DMODEL * 2;
    const size_t QH_BYTES = (size_t)BATCH * SEQ * HD * 2;

    float*    Vv  = (float*)(ws);
    float*    sc  = (float*)(ws + V_BYTES);
    _Float16* Whi = (_Float16*)(ws + V_BYTES + SC_BYTES);
    _Float16* Wlo = (_Float16*)(ws + V_BYTES + SC_BYTES + WH_BYTES);
    _Float16* QH  = (_Float16*)(ws + V_BYTES + SC_BYTES + 2 * WH_BYTES);
    _Float16* QL  = (_Float16*)(ws + V_BYTES + SC_BYTES + 2 * WH_BYTES + QH_BYTES);
    _Float16* KH  = (_Float16*)(ws + V_BYTES + SC_BYTES + 2 * WH_BYTES + 2 * QH_BYTES);
    _Float16* KL  = (_Float16*)(ws + V_BYTES + SC_BYTES + 2 * WH_BYTES + 3 * QH_BYTES);

    wsplit_kernel<<<EE, 256, 0, stream>>>(W, Whi, Wlo);
    qkv_mfma_kernel<<<dim3(256, 2), 256, 0, stream>>>(X, Whi, Wlo, QH, QL, KH, KL, Vv);
    for (int b = 0; b < BATCH; ++b) {
        scores_mfma_kernel<<<dim3(64, 32), 256, 0, stream>>>(
            QH + (size_t)b * SEQ * HD, QL + (size_t)b * SEQ * HD,
            KH + (size_t)b * SEQ * HD, KL + (size_t)b * SEQ * HD, sc);
        topk_attn_kernel<<<SEQ, 256, 0, stream>>>(Vv, sc, Out, b);
    }
}